// Round 6
// baseline (299.265 us; speedup 1.0000x reference)
//
#include <hip/hip_runtime.h>
#include <hip/hip_bf16.h>
#include <math.h>

// (B, D, H, W, K) = (32, 256, 64, 64, 64); N = H*W = 4096
#define BB 32
#define DD 256
#define NN 4096
#define KK 64
#define EPSV 1e-8f
#define XSTR 264   // xnd row stride (shorts): 528 B = 16B-aligned, bank-rotating

typedef __attribute__((ext_vector_type(8))) short short8;   // 8 bf16
typedef __attribute__((ext_vector_type(4))) float f32x4;

__device__ __forceinline__ unsigned int bf16pair(float a, float b) {
    __hip_bfloat162 h = __float22bfloat162_rn(make_float2(a, b));  // v_cvt_pk_bf16_f32 (RNE)
    return *(unsigned int*)&h;
}
__device__ __forceinline__ unsigned short bf16one(float a) {
    unsigned int ua = __float_as_uint(a);
    ua += 0x7fffu + ((ua >> 16) & 1u);
    return (unsigned short)(ua >> 16);
}

// stage one 4d x 4n register subtile into xdn (d-major) and xnd (n-major)
__device__ __forceinline__ void stage_group(int dbase, int n4, const float4* rr,
                                            unsigned short* xnd_s, unsigned short* xdn_s,
                                            f32x4& ssn) {
    float4 r0 = rr[0], r1 = rr[1], r2 = rr[2], r3 = rr[3];
    ssn.x = fmaf(r0.x, r0.x, ssn.x); ssn.x = fmaf(r1.x, r1.x, ssn.x);
    ssn.x = fmaf(r2.x, r2.x, ssn.x); ssn.x = fmaf(r3.x, r3.x, ssn.x);
    ssn.y = fmaf(r0.y, r0.y, ssn.y); ssn.y = fmaf(r1.y, r1.y, ssn.y);
    ssn.y = fmaf(r2.y, r2.y, ssn.y); ssn.y = fmaf(r3.y, r3.y, ssn.y);
    ssn.z = fmaf(r0.z, r0.z, ssn.z); ssn.z = fmaf(r1.z, r1.z, ssn.z);
    ssn.z = fmaf(r2.z, r2.z, ssn.z); ssn.z = fmaf(r3.z, r3.z, ssn.z);
    ssn.w = fmaf(r0.w, r0.w, ssn.w); ssn.w = fmaf(r1.w, r1.w, ssn.w);
    ssn.w = fmaf(r2.w, r2.w, ssn.w); ssn.w = fmaf(r3.w, r3.w, ssn.w);
#pragma unroll
    for (int j = 0; j < 4; j++) {  // xdn: row d, 4 consecutive n -> b64
        int d = dbase + j;
        uint2 u;
        u.x = bf16pair(rr[j].x, rr[j].y);
        u.y = bf16pair(rr[j].z, rr[j].w);
        *(uint2*)(xdn_s + d * 64 + ((((n4 >> 3) ^ (d & 7)) << 3) | (n4 & 7))) = u;
    }
    {  // xnd: row n, 4 consecutive d -> b64 (register transpose)
        float col[4][4] = {{r0.x, r1.x, r2.x, r3.x},
                           {r0.y, r1.y, r2.y, r3.y},
                           {r0.z, r1.z, r2.z, r3.z},
                           {r0.w, r1.w, r2.w, r3.w}};
#pragma unroll
        for (int j = 0; j < 4; j++) {
            int n = n4 + j;
            uint2 u;
            u.x = bf16pair(col[j][0], col[j][1]);
            u.y = bf16pair(col[j][2], col[j][3]);
            int blk = (dbase >> 3) ^ ((n >> 2) & 3);
            *(uint2*)(xnd_s + n * XSTR + (blk << 3) + (dbase & 7)) = u;
        }
    }
}

// ---------------- fused: L-GEMM -> softmax -> agg-GEMM ----------------
// grid 512 = 32 b x 16 chunks of 256 n; 4 passes of 64 n; 4 waves.
// Wave w: k-range [16w,16w+16) for L-GEMM (Cn frags in regs); d-range
// [64w,64w+64) for agg-GEMM. LDS 76 KB -> 2 blocks/CU.
// R6: pre[8]+cur[8] prefetch split (fits 128 arch VGPRs -> no spill, loads
// stay in flight across barriers); E accumulated via atomicAdd into d_out
// (P partials + 33.5 MB ws eliminated).
__global__ __launch_bounds__(256, 2) void k_fused(const float* __restrict__ X,
                                                  const float* __restrict__ C,
                                                  float* __restrict__ out,
                                                  float* __restrict__ Sg) {
    __shared__ unsigned short xnd_s[64 * XSTR];  // [n][d] bf16, 33792 B
    __shared__ unsigned short xdn_s[DD * 64];    // [d][n] bf16, 32768 B
    __shared__ unsigned short at_s[KK * 72];     // [k][n] bf16, 9216 B
    __shared__ float rn4[4 * 64];                // per-wave partial ||x_n||^2
    __shared__ float red_s[4 * 64];              // per-wave exp-sum [w][n]

    int t = threadIdx.x;
    int b = blockIdx.x >> 4, chunk = blockIdx.x & 15;
    int w = t >> 6, lane = t & 63, c = lane & 15, g = lane >> 4;
    int q = t >> 4;  // 4w + g
    int n4 = c * 4;

    const float* Xb = X + (size_t)b * DD * NN + chunk * 256;

    // ---- initial prefetch (pass 0, d-half 0): 8 float4 = 32 VGPRs ----
    float4 pre[8];
#pragma unroll
    for (int i = 0; i < 2; i++) {
        const float* xb = Xb + (size_t)(q * 4 + 64 * i) * NN + n4;
#pragma unroll
        for (int j = 0; j < 4; j++) pre[i * 4 + j] = *(const float4*)(xb + (size_t)j * NN);
    }

    // ---- codeword fragments in registers + on-the-fly row norm ----
    short8 cnf[8];
    {
        int k = 16 * w + c;
        const float* cp = C + k * DD;
        float4 v0[8], v1[8];
        float ss = 0.f;
#pragma unroll
        for (int ks = 0; ks < 8; ks++) {
            v0[ks] = *(const float4*)(cp + 32 * ks + 8 * g);
            v1[ks] = *(const float4*)(cp + 32 * ks + 8 * g + 4);
            ss = fmaf(v0[ks].x, v0[ks].x, ss); ss = fmaf(v0[ks].y, v0[ks].y, ss);
            ss = fmaf(v0[ks].z, v0[ks].z, ss); ss = fmaf(v0[ks].w, v0[ks].w, ss);
            ss = fmaf(v1[ks].x, v1[ks].x, ss); ss = fmaf(v1[ks].y, v1[ks].y, ss);
            ss = fmaf(v1[ks].z, v1[ks].z, ss); ss = fmaf(v1[ks].w, v1[ks].w, ss);
        }
        ss += __shfl_xor(ss, 16);
        ss += __shfl_xor(ss, 32);
        float r = 1.f / fmaxf(sqrtf(ss), EPSV);
#pragma unroll
        for (int ks = 0; ks < 8; ks++) {
            uint4 u;
            u.x = bf16pair(v0[ks].x * r, v0[ks].y * r);
            u.y = bf16pair(v0[ks].z * r, v0[ks].w * r);
            u.z = bf16pair(v1[ks].x * r, v1[ks].y * r);
            u.w = bf16pair(v1[ks].z * r, v1[ks].w * r);
            cnf[ks] = *(short8*)&u;
        }
    }

    f32x4 eacc[4][4];
#pragma unroll
    for (int dt = 0; dt < 4; dt++)
#pragma unroll
        for (int kt = 0; kt < 4; kt++) eacc[dt][kt] = (f32x4){0.f, 0.f, 0.f, 0.f};
    float s_acc[4] = {0.f, 0.f, 0.f, 0.f};

    for (int p = 0; p < 4; p++) {
        // ---- issue d-half 1 of THIS pass before the barrier (reg-dest loads
        //      don't force a vmcnt drain at s_barrier) ----
        float4 cur[8];
#pragma unroll
        for (int i = 0; i < 2; i++) {
            const float* xb = Xb + (size_t)(q * 4 + 64 * (2 + i)) * NN + p * 64 + n4;
#pragma unroll
            for (int j = 0; j < 4; j++) cur[i * 4 + j] = *(const float4*)(xb + (size_t)j * NN);
        }
        __syncthreads();  // (A) prev-pass LDS reads done; staging may rewrite

        // ---- consume pre (d 0..127) while cur is in flight, then cur ----
        f32x4 ssn = (f32x4){0.f, 0.f, 0.f, 0.f};
#pragma unroll
        for (int i = 0; i < 2; i++)
            stage_group(q * 4 + 64 * i, n4, &pre[i * 4], xnd_s, xdn_s, ssn);
#pragma unroll
        for (int i = 0; i < 2; i++)
            stage_group(q * 4 + 64 * (2 + i), n4, &cur[i * 4], xnd_s, xdn_s, ssn);

        // ---- issue NEXT pass's d-half 0: in flight across all barriers below ----
        if (p < 3) {
#pragma unroll
            for (int i = 0; i < 2; i++) {
                const float* xb = Xb + (size_t)(q * 4 + 64 * i) * NN + (p + 1) * 64 + n4;
#pragma unroll
                for (int j = 0; j < 4; j++) pre[i * 4 + j] = *(const float4*)(xb + (size_t)j * NN);
            }
        }

        // ---- row-norm partials: reduce over g via shfl, write rn4[w][n] ----
        ssn.x += __shfl_xor(ssn.x, 16); ssn.x += __shfl_xor(ssn.x, 32);
        ssn.y += __shfl_xor(ssn.y, 16); ssn.y += __shfl_xor(ssn.y, 32);
        ssn.z += __shfl_xor(ssn.z, 16); ssn.z += __shfl_xor(ssn.z, 32);
        ssn.w += __shfl_xor(ssn.w, 16); ssn.w += __shfl_xor(ssn.w, 32);
        if (g == 0) *(f32x4*)(rn4 + w * 64 + n4) = ssn;

        __syncthreads();  // (B) staging + rn4 visible

        // ---- L-GEMM: Lt[16w..16w+16 k][64 n] ----
        f32x4 lacc[4];
#pragma unroll
        for (int nt = 0; nt < 4; nt++) lacc[nt] = (f32x4){0.f, 0.f, 0.f, 0.f};
#pragma unroll
        for (int ks = 0; ks < 8; ks++) {
            short8 af = cnf[ks];
#pragma unroll
            for (int nt = 0; nt < 4; nt++) {
                int n = nt * 16 + c;
                short8 bf = *(const short8*)(xnd_s + n * XSTR +
                                             (((4 * ks + g) ^ ((n >> 2) & 3)) << 3));
                lacc[nt] = __builtin_amdgcn_mfma_f32_16x16x32_bf16(af, bf, lacc[nt], 0, 0, 0);
            }
        }

        // ---- softmax (no max-subtract: cosine sims are in [-1,1]) ----
        float lv[4][4];
#pragma unroll
        for (int nt = 0; nt < 4; nt++) {
            int n = nt * 16 + c;
            float ssq = rn4[n] + rn4[64 + n] + rn4[128 + n] + rn4[192 + n];
            float rn = 1.f / fmaxf(sqrtf(ssq), EPSV);
            float s = 0.f;
#pragma unroll
            for (int r = 0; r < 4; r++) {
                lv[nt][r] = __expf(lacc[nt][r] * rn);
                s += lv[nt][r];
            }
            s += __shfl_xor(s, 16);
            s += __shfl_xor(s, 32);
            if (g == 0) red_s[w * 64 + n] = s;
        }
        __syncthreads();  // (D) red_s visible

#pragma unroll
        for (int nt = 0; nt < 4; nt++) {
            int n = nt * 16 + c;
            float denom = red_s[n] + red_s[64 + n] + red_s[128 + n] + red_s[192 + n];
            float inv = 1.f / denom;
#pragma unroll
            for (int r = 0; r < 4; r++) {
                float a = lv[nt][r] * inv;
                s_acc[r] += a;
                int k = 16 * w + 4 * g + r;
                at_s[k * 72 + ((((n >> 3) ^ (k & 7)) << 3) | (n & 7))] = bf16one(a);
            }
        }
        __syncthreads();  // (E) at_s visible

        // ---- agg-GEMM: Et[d = 64w..][k] += sum_n X[n][d] * A[n][k] ----
#pragma unroll
        for (int ks2 = 0; ks2 < 2; ks2++) {
            short8 bk[4];
#pragma unroll
            for (int kt = 0; kt < 4; kt++) {
                int k = kt * 16 + c;
                bk[kt] = *(const short8*)(at_s + k * 72 + (((4 * ks2 + g) ^ (k & 7)) << 3));
            }
#pragma unroll
            for (int dt = 0; dt < 4; dt++) {
                int d = w * 64 + dt * 16 + c;
                short8 af = *(const short8*)(xdn_s + d * 64 + (((4 * ks2 + g) ^ (d & 7)) << 3));
#pragma unroll
                for (int kt = 0; kt < 4; kt++)
                    eacc[dt][kt] =
                        __builtin_amdgcn_mfma_f32_16x16x32_bf16(af, bk[kt], eacc[dt][kt], 0, 0, 0);
            }
        }
    }

    // ---- epilogue: atomic E into out[b][k][d]; atomic S into Sg[b][k] ----
    float* ob = out + (size_t)b * (KK * DD);
#pragma unroll
    for (int dt = 0; dt < 4; dt++)
#pragma unroll
        for (int kt = 0; kt < 4; kt++) {
            int k = kt * 16 + c;
#pragma unroll
            for (int r = 0; r < 4; r++) {
                int d = w * 64 + dt * 16 + 4 * g + r;
                atomicAdd(&ob[k * DD + d], eacc[dt][kt][r]);
            }
        }
#pragma unroll
    for (int r = 0; r < 4; r++) {
        float v = s_acc[r];
        v += __shfl_xor(v, 1);
        v += __shfl_xor(v, 2);
        v += __shfl_xor(v, 4);
        v += __shfl_xor(v, 8);
        if (c == 0) atomicAdd(&Sg[b * 64 + 16 * w + 4 * g + r], v);
    }
}

// ---------- finalize: out -= S*C ----------
__global__ __launch_bounds__(256) void k_fin(const float* __restrict__ Sg,
                                             const float* __restrict__ C,
                                             float* __restrict__ out) {
    int idx = blockIdx.x * 256 + threadIdx.x;  // 524288; d consecutive -> coalesced
    int d = idx & 255;
    int k = (idx >> 8) & 63;
    int b = idx >> 14;
    out[idx] -= Sg[b * 64 + k] * C[k * 256 + d];  // Sg wave-uniform (scalar load)
}

// ---------- launch ----------
extern "C" void kernel_launch(void* const* d_in, const int* in_sizes, int n_in,
                              void* d_out, int out_size, void* d_ws, size_t ws_size,
                              hipStream_t stream) {
    const float* X = (const float*)d_in[0];
    const float* C = (const float*)d_in[1];
    float* out = (float*)d_out;
    float* Sg = (float*)d_ws;  // 32*64*4 = 8 KB

    hipMemsetAsync(out, 0, (size_t)out_size * sizeof(float), stream);
    hipMemsetAsync(Sg, 0, BB * KK * sizeof(float), stream);
    k_fused<<<512, 256, 0, stream>>>(X, C, out, Sg);
    k_fin<<<2048, 256, 0, stream>>>(Sg, C, out);
}

// Round 7
// 214.247 us; speedup vs baseline: 1.3968x; 1.3968x over previous
//
#include <hip/hip_runtime.h>
#include <hip/hip_bf16.h>
#include <math.h>

// (B, D, H, W, K) = (32, 256, 64, 64, 64); N = H*W = 4096
#define BB 32
#define DD 256
#define NN 4096
#define KK 64
#define EPSV 1e-8f
#define XSTR 264   // xnd row stride (shorts): 528 B = 16B-aligned, bank-rotating

typedef __attribute__((ext_vector_type(8))) short short8;   // 8 bf16
typedef __attribute__((ext_vector_type(4))) float f32x4;

__device__ __forceinline__ unsigned int bf16pair(float a, float b) {
    __hip_bfloat162 h = __float22bfloat162_rn(make_float2(a, b));  // v_cvt_pk_bf16_f32 (RNE)
    return *(unsigned int*)&h;
}
__device__ __forceinline__ unsigned short bf16one(float a) {
    unsigned int ua = __float_as_uint(a);
    ua += 0x7fffu + ((ua >> 16) & 1u);
    return (unsigned short)(ua >> 16);
}

// stage one 4d x 4n register subtile into xdn (d-major) and xnd (n-major)
__device__ __forceinline__ void stage_group(int dbase, int n4, const float4* rr,
                                            unsigned short* xnd_s, unsigned short* xdn_s,
                                            f32x4& ssn) {
    float4 r0 = rr[0], r1 = rr[1], r2 = rr[2], r3 = rr[3];
    ssn.x = fmaf(r0.x, r0.x, ssn.x); ssn.x = fmaf(r1.x, r1.x, ssn.x);
    ssn.x = fmaf(r2.x, r2.x, ssn.x); ssn.x = fmaf(r3.x, r3.x, ssn.x);
    ssn.y = fmaf(r0.y, r0.y, ssn.y); ssn.y = fmaf(r1.y, r1.y, ssn.y);
    ssn.y = fmaf(r2.y, r2.y, ssn.y); ssn.y = fmaf(r3.y, r3.y, ssn.y);
    ssn.z = fmaf(r0.z, r0.z, ssn.z); ssn.z = fmaf(r1.z, r1.z, ssn.z);
    ssn.z = fmaf(r2.z, r2.z, ssn.z); ssn.z = fmaf(r3.z, r3.z, ssn.z);
    ssn.w = fmaf(r0.w, r0.w, ssn.w); ssn.w = fmaf(r1.w, r1.w, ssn.w);
    ssn.w = fmaf(r2.w, r2.w, ssn.w); ssn.w = fmaf(r3.w, r3.w, ssn.w);
#pragma unroll
    for (int j = 0; j < 4; j++) {  // xdn: row d, 4 consecutive n -> b64
        int d = dbase + j;
        uint2 u;
        u.x = bf16pair(rr[j].x, rr[j].y);
        u.y = bf16pair(rr[j].z, rr[j].w);
        *(uint2*)(xdn_s + d * 64 + ((((n4 >> 3) ^ (d & 7)) << 3) | (n4 & 7))) = u;
    }
    {  // xnd: row n, 4 consecutive d -> b64 (register transpose)
        float col[4][4] = {{r0.x, r1.x, r2.x, r3.x},
                           {r0.y, r1.y, r2.y, r3.y},
                           {r0.z, r1.z, r2.z, r3.z},
                           {r0.w, r1.w, r2.w, r3.w}};
#pragma unroll
        for (int j = 0; j < 4; j++) {
            int n = n4 + j;
            uint2 u;
            u.x = bf16pair(col[j][0], col[j][1]);
            u.y = bf16pair(col[j][2], col[j][3]);
            int blk = (dbase >> 3) ^ ((n >> 2) & 3);
            *(uint2*)(xnd_s + n * XSTR + (blk << 3) + (dbase & 7)) = u;
        }
    }
}

// ---------------- fused: L-GEMM -> softmax -> agg-GEMM ----------------
// grid 512 = 32 b x 16 chunks of 256 n; 4 passes of 64 n; 4 waves.
// Wave w: k-range [16w,16w+16) for L-GEMM (Cn frags in regs); d-range
// [64w,64w+64) for agg-GEMM. LDS 76 KB -> 2 blocks/CU.
// R7 = R6's no-spill pre[8]/cur[8] register prefetch (FETCH stays ~66 MB)
//    + R5's P-partials epilogue (R6's atomicAdd-to-out wrote 134 MB through
//      the coherent path and serialized: 175 us, MfmaUtil 1.9%).
__global__ __launch_bounds__(256, 2) void k_fused(const float* __restrict__ X,
                                                  const float* __restrict__ C,
                                                  float* __restrict__ P,
                                                  float* __restrict__ Sp) {
    __shared__ unsigned short xnd_s[64 * XSTR];  // [n][d] bf16, 33792 B
    __shared__ unsigned short xdn_s[DD * 64];    // [d][n] bf16, 32768 B
    __shared__ unsigned short at_s[KK * 72];     // [k][n] bf16, 9216 B
    __shared__ float rn4[4 * 64];                // per-wave partial ||x_n||^2
    __shared__ float red_s[4 * 64];              // per-wave exp-sum [w][n]

    int t = threadIdx.x;
    int b = blockIdx.x >> 4, chunk = blockIdx.x & 15;
    int w = t >> 6, lane = t & 63, c = lane & 15, g = lane >> 4;
    int q = t >> 4;  // 4w + g
    int n4 = c * 4;

    const float* Xb = X + (size_t)b * DD * NN + chunk * 256;

    // ---- initial prefetch (pass 0, d-half 0): 8 float4 = 32 VGPRs ----
    float4 pre[8];
#pragma unroll
    for (int i = 0; i < 2; i++) {
        const float* xb = Xb + (size_t)(q * 4 + 64 * i) * NN + n4;
#pragma unroll
        for (int j = 0; j < 4; j++) pre[i * 4 + j] = *(const float4*)(xb + (size_t)j * NN);
    }

    // ---- codeword fragments in registers + on-the-fly row norm ----
    short8 cnf[8];
    {
        int k = 16 * w + c;
        const float* cp = C + k * DD;
        float4 v0[8], v1[8];
        float ss = 0.f;
#pragma unroll
        for (int ks = 0; ks < 8; ks++) {
            v0[ks] = *(const float4*)(cp + 32 * ks + 8 * g);
            v1[ks] = *(const float4*)(cp + 32 * ks + 8 * g + 4);
            ss = fmaf(v0[ks].x, v0[ks].x, ss); ss = fmaf(v0[ks].y, v0[ks].y, ss);
            ss = fmaf(v0[ks].z, v0[ks].z, ss); ss = fmaf(v0[ks].w, v0[ks].w, ss);
            ss = fmaf(v1[ks].x, v1[ks].x, ss); ss = fmaf(v1[ks].y, v1[ks].y, ss);
            ss = fmaf(v1[ks].z, v1[ks].z, ss); ss = fmaf(v1[ks].w, v1[ks].w, ss);
        }
        ss += __shfl_xor(ss, 16);
        ss += __shfl_xor(ss, 32);
        float r = 1.f / fmaxf(sqrtf(ss), EPSV);
#pragma unroll
        for (int ks = 0; ks < 8; ks++) {
            uint4 u;
            u.x = bf16pair(v0[ks].x * r, v0[ks].y * r);
            u.y = bf16pair(v0[ks].z * r, v0[ks].w * r);
            u.z = bf16pair(v1[ks].x * r, v1[ks].y * r);
            u.w = bf16pair(v1[ks].z * r, v1[ks].w * r);
            cnf[ks] = *(short8*)&u;
        }
    }

    f32x4 eacc[4][4];
#pragma unroll
    for (int dt = 0; dt < 4; dt++)
#pragma unroll
        for (int kt = 0; kt < 4; kt++) eacc[dt][kt] = (f32x4){0.f, 0.f, 0.f, 0.f};
    float s_acc[4] = {0.f, 0.f, 0.f, 0.f};

    for (int p = 0; p < 4; p++) {
        // ---- issue d-half 1 of THIS pass before the barrier (reg-dest loads
        //      don't force a vmcnt drain at s_barrier) ----
        float4 cur[8];
#pragma unroll
        for (int i = 0; i < 2; i++) {
            const float* xb = Xb + (size_t)(q * 4 + 64 * (2 + i)) * NN + p * 64 + n4;
#pragma unroll
            for (int j = 0; j < 4; j++) cur[i * 4 + j] = *(const float4*)(xb + (size_t)j * NN);
        }
        __syncthreads();  // (A) prev-pass LDS reads done; staging may rewrite

        // ---- consume pre (d 0..127) while cur is in flight, then cur ----
        f32x4 ssn = (f32x4){0.f, 0.f, 0.f, 0.f};
#pragma unroll
        for (int i = 0; i < 2; i++)
            stage_group(q * 4 + 64 * i, n4, &pre[i * 4], xnd_s, xdn_s, ssn);
#pragma unroll
        for (int i = 0; i < 2; i++)
            stage_group(q * 4 + 64 * (2 + i), n4, &cur[i * 4], xnd_s, xdn_s, ssn);

        // ---- issue NEXT pass's d-half 0: in flight across all barriers below ----
        if (p < 3) {
#pragma unroll
            for (int i = 0; i < 2; i++) {
                const float* xb = Xb + (size_t)(q * 4 + 64 * i) * NN + (p + 1) * 64 + n4;
#pragma unroll
                for (int j = 0; j < 4; j++) pre[i * 4 + j] = *(const float4*)(xb + (size_t)j * NN);
            }
        }

        // ---- row-norm partials: reduce over g via shfl, write rn4[w][n] ----
        ssn.x += __shfl_xor(ssn.x, 16); ssn.x += __shfl_xor(ssn.x, 32);
        ssn.y += __shfl_xor(ssn.y, 16); ssn.y += __shfl_xor(ssn.y, 32);
        ssn.z += __shfl_xor(ssn.z, 16); ssn.z += __shfl_xor(ssn.z, 32);
        ssn.w += __shfl_xor(ssn.w, 16); ssn.w += __shfl_xor(ssn.w, 32);
        if (g == 0) *(f32x4*)(rn4 + w * 64 + n4) = ssn;

        __syncthreads();  // (B) staging + rn4 visible

        // ---- L-GEMM: Lt[16w..16w+16 k][64 n] ----
        f32x4 lacc[4];
#pragma unroll
        for (int nt = 0; nt < 4; nt++) lacc[nt] = (f32x4){0.f, 0.f, 0.f, 0.f};
#pragma unroll
        for (int ks = 0; ks < 8; ks++) {
            short8 af = cnf[ks];
#pragma unroll
            for (int nt = 0; nt < 4; nt++) {
                int n = nt * 16 + c;
                short8 bf = *(const short8*)(xnd_s + n * XSTR +
                                             (((4 * ks + g) ^ ((n >> 2) & 3)) << 3));
                lacc[nt] = __builtin_amdgcn_mfma_f32_16x16x32_bf16(af, bf, lacc[nt], 0, 0, 0);
            }
        }

        // ---- softmax (no max-subtract: cosine sims are in [-1,1]) ----
        float lv[4][4];
#pragma unroll
        for (int nt = 0; nt < 4; nt++) {
            int n = nt * 16 + c;
            float ssq = rn4[n] + rn4[64 + n] + rn4[128 + n] + rn4[192 + n];
            float rn = 1.f / fmaxf(sqrtf(ssq), EPSV);
            float s = 0.f;
#pragma unroll
            for (int r = 0; r < 4; r++) {
                lv[nt][r] = __expf(lacc[nt][r] * rn);
                s += lv[nt][r];
            }
            s += __shfl_xor(s, 16);
            s += __shfl_xor(s, 32);
            if (g == 0) red_s[w * 64 + n] = s;
        }
        __syncthreads();  // (D) red_s visible

#pragma unroll
        for (int nt = 0; nt < 4; nt++) {
            int n = nt * 16 + c;
            float denom = red_s[n] + red_s[64 + n] + red_s[128 + n] + red_s[192 + n];
            float inv = 1.f / denom;
#pragma unroll
            for (int r = 0; r < 4; r++) {
                float a = lv[nt][r] * inv;
                s_acc[r] += a;
                int k = 16 * w + 4 * g + r;
                at_s[k * 72 + ((((n >> 3) ^ (k & 7)) << 3) | (n & 7))] = bf16one(a);
            }
        }
        __syncthreads();  // (E) at_s visible

        // ---- agg-GEMM: Et[d = 64w..][k] += sum_n X[n][d] * A[n][k] ----
#pragma unroll
        for (int ks2 = 0; ks2 < 2; ks2++) {
            short8 bk[4];
#pragma unroll
            for (int kt = 0; kt < 4; kt++) {
                int k = kt * 16 + c;
                bk[kt] = *(const short8*)(at_s + k * 72 + (((4 * ks2 + g) ^ (k & 7)) << 3));
            }
#pragma unroll
            for (int dt = 0; dt < 4; dt++) {
                int d = w * 64 + dt * 16 + c;
                short8 af = *(const short8*)(xdn_s + d * 64 + (((4 * ks2 + g) ^ (d & 7)) << 3));
#pragma unroll
                for (int kt = 0; kt < 4; kt++)
                    eacc[dt][kt] =
                        __builtin_amdgcn_mfma_f32_16x16x32_bf16(af, bk[kt], eacc[dt][kt], 0, 0, 0);
            }
        }
    }

    // ---- epilogue: partials P[block][d][k] + per-block S ----
    float* Pb = P + (size_t)blockIdx.x * (DD * KK);
#pragma unroll
    for (int dt = 0; dt < 4; dt++)
#pragma unroll
        for (int kt = 0; kt < 4; kt++)
#pragma unroll
            for (int r = 0; r < 4; r++) {
                int d = w * 64 + dt * 16 + 4 * g + r;
                Pb[d * 64 + kt * 16 + c] = eacc[dt][kt][r];
            }
#pragma unroll
    for (int r = 0; r < 4; r++) {
        float v = s_acc[r];
        v += __shfl_xor(v, 1);
        v += __shfl_xor(v, 2);
        v += __shfl_xor(v, 4);
        v += __shfl_xor(v, 8);
        if (c == 0) Sp[blockIdx.x * 64 + 16 * w + 4 * g + r] = v;
    }
}

// ---------- finalize: sum 16 partials, subtract S*C ----------
__global__ __launch_bounds__(256) void k_fin(const float* __restrict__ P,
                                             const float* __restrict__ Sp,
                                             const float* __restrict__ C,
                                             float* __restrict__ out) {
    int idx = blockIdx.x * 256 + threadIdx.x;  // 524288 total
    int b = idx >> 14;
    int r = idx & 16383;
    int d = r >> 6;
    int k = r & 63;  // consecutive threads -> consecutive k: coalesced P reads
    float e = 0.f, s = 0.f;
    int base = b * 16;
#pragma unroll
    for (int cc = 0; cc < 16; cc++) {
        e += P[(size_t)(base + cc) * (DD * KK) + d * 64 + k];
        s += Sp[(base + cc) * 64 + k];
    }
    out[(size_t)(b * 64 + k) * 256 + d] = e - s * C[k * 256 + d];
}

// ---------- launch ----------
extern "C" void kernel_launch(void* const* d_in, const int* in_sizes, int n_in,
                              void* d_out, int out_size, void* d_ws, size_t ws_size,
                              hipStream_t stream) {
    const float* X = (const float*)d_in[0];
    const float* C = (const float*)d_in[1];
    float* out = (float*)d_out;
    unsigned char* ws = (unsigned char*)d_ws;

    // ws: Sp 512*64*4 = 131072 B | P 512*256*64*4 = 33554432 B
    float* Sp = (float*)ws;
    float* P = (float*)(ws + 131072);

    k_fused<<<512, 256, 0, stream>>>(X, C, P, Sp);
    k_fin<<<2048, 256, 0, stream>>>(P, Sp, C, out);
}